// Round 9
// baseline (4070.804 us; speedup 1.0000x reference)
//
#include <hip/hip_runtime.h>
#include <math.h>

#define DD 384
#define HH 12
#define DKK 32
#define LL 6
#define FFF 1536
#define BB 64
#define SS 512
#define MROWS (BB*SS)   // 32768
#define TB 32           // scan time-tile
#define LDX 1152        // qkv row stride

typedef _Float16 f16;
typedef _Float16 half8 __attribute__((ext_vector_type(8)));
typedef _Float16 h2 __attribute__((ext_vector_type(2)));
typedef float f32x4 __attribute__((ext_vector_type(4)));

__device__ __forceinline__ float sigmoidf_(float x){ return 1.0f/(1.0f+expf(-x)); }

__device__ __forceinline__ void gl2lds16(const void* g, void* l){
  __builtin_amdgcn_global_load_lds((const __attribute__((address_space(1))) void*)g,
                                   (__attribute__((address_space(3))) void*)l, 16, 0, 0);
}

// ---------------- embedding + LN (writes fp32 x and f16 xh) ----------------
__global__ __launch_bounds__(256) void embed_ln_kernel(
    const int* __restrict__ ids, const float* __restrict__ we,
    const float* __restrict__ pe, const float* __restrict__ te,
    const float* __restrict__ w, const float* __restrict__ b,
    float* __restrict__ x, f16* __restrict__ xh)
{
  int wv = threadIdx.x >> 6, lane = threadIdx.x & 63;
  int row = blockIdx.x * 4 + wv;
  int s = row & (SS-1);
  int id = ids[row];
  const float* wep = we + (size_t)id * DD;
  const float* pep = pe + (size_t)s * DD;
  float vals[6]; float sum = 0.f;
  #pragma unroll
  for (int i=0;i<6;i++){ int d = lane + 64*i; vals[i] = wep[d] + pep[d] + te[d]; sum += vals[i]; }
  #pragma unroll
  for (int off=32; off>=1; off>>=1) sum += __shfl_xor(sum, off);
  float mean = sum * (1.0f/DD);
  float vs = 0.f;
  #pragma unroll
  for (int i=0;i<6;i++){ float dv = vals[i]-mean; vs += dv*dv; }
  #pragma unroll
  for (int off=32; off>=1; off>>=1) vs += __shfl_xor(vs, off);
  float inv = rsqrtf(vs*(1.0f/DD) + 1e-12f);
  float* xr = x + (size_t)row*DD;
  f16* xhr = xh + (size_t)row*DD;
  #pragma unroll
  for (int i=0;i<6;i++){ int d = lane + 64*i; float o = (vals[i]-mean)*inv*w[d] + b[d]; xr[d]=o; xhr[d]=(f16)o; }
}

// ---------------- x = LN(x + y); y f32 (YH=0) or f16 (YH=1), stride ldy ----------------
template<int YH>
__global__ __launch_bounds__(256) void add_ln_kernel(
    float* __restrict__ x, f16* __restrict__ xh, const void* __restrict__ yp,
    const float* __restrict__ w, const float* __restrict__ b, int row0, int ldy)
{
  int wv = threadIdx.x >> 6, lane = threadIdx.x & 63;
  int rrel = blockIdx.x * 4 + wv;
  int row = row0 + rrel;
  float* xr = x + (size_t)row*DD;
  f16* xhr = xh + (size_t)row*DD;
  float vals[6]; float sum = 0.f;
  #pragma unroll
  for (int i=0;i<6;i++){
    int d = lane + 64*i;
    float yv;
    if (YH) yv = (float)((const f16*)yp)[(size_t)rrel*ldy + d];
    else    yv = ((const float*)yp)[(size_t)rrel*ldy + d];
    vals[i] = xr[d] + yv; sum += vals[i];
  }
  #pragma unroll
  for (int off=32; off>=1; off>>=1) sum += __shfl_xor(sum, off);
  float mean = sum * (1.0f/DD);
  float vs = 0.f;
  #pragma unroll
  for (int i=0;i<6;i++){ float dv = vals[i]-mean; vs += dv*dv; }
  #pragma unroll
  for (int off=32; off>=1; off>>=1) vs += __shfl_xor(vs, off);
  float inv = rsqrtf(vs*(1.0f/DD) + 1e-12f);
  #pragma unroll
  for (int i=0;i<6;i++){ int d = lane + 64*i; float o = (vals[i]-mean)*inv*w[d] + b[d]; xr[d]=o; xhr[d]=(f16)o; }
}

// ---------------- bias pack: [bq;bk;bv] per layer -> 1152 each ----------------
__global__ __launch_bounds__(256) void biaspack_kernel(
    const float* __restrict__ bq, const float* __restrict__ bk, const float* __restrict__ bv,
    float* __restrict__ dst)
{
  int i = blockIdx.x*256 + threadIdx.x;   // 6912 total
  if (i >= LL*LDX) return;
  int l = i / LDX, r = i - l*LDX;
  float v;
  if (r < 384) v = bq[l*DD + r];
  else if (r < 768) v = bk[l*DD + r-384];
  else v = bv[l*DD + r-768];
  dst[i] = v;
}

// ---------------- weight transpose + f32->f16, ALL layers in one dispatch ----------------
__global__ __launch_bounds__(256) void wtrans_kernel(
  const float* __restrict__ Wq, const float* __restrict__ Wk, const float* __restrict__ Wv,
  const float* __restrict__ Wo, const float* __restrict__ W1, const float* __restrict__ W2,
  f16* __restrict__ Wt)
{
  __shared__ float T[32][33];
  int l = blockIdx.x / 1728, bidx = blockIdx.x % 1728;
  const float* src; f16* dst; int K, N, tile;
  if (bidx < 576){ int m = bidx/144; tile = bidx - m*144; K=384; N=384;
    const float* w4[4] = {Wq + (size_t)l*147456, Wk + (size_t)l*147456,
                          Wv + (size_t)l*147456, Wo + (size_t)l*147456};
    src = w4[m]; dst = Wt + (size_t)l*1769472 + m*147456; }
  else if (bidx < 1152){ tile = bidx-576; K=384; N=1536;
    src = W1 + (size_t)l*589824; dst = Wt + (size_t)l*1769472 + 589824; }
  else { tile = bidx-1152; K=1536; N=384;
    src = W2 + (size_t)l*589824; dst = Wt + (size_t)l*1769472 + 1179648; }
  int tN = N>>5;
  int tk = tile / tN, tn = tile - tk*tN;
  int k0 = tk<<5, n0 = tn<<5;
  int r = threadIdx.x >> 3, c4 = (threadIdx.x & 7) << 2;
  float4 vv = *(const float4*)(src + (size_t)(k0+r)*N + n0 + c4);
  T[r][c4+0]=vv.x; T[r][c4+1]=vv.y; T[r][c4+2]=vv.z; T[r][c4+3]=vv.w;
  __syncthreads();
  f16* dp = dst + (size_t)(n0+r)*K + k0 + c4;
  #pragma unroll
  for (int j=0;j<4;j++) dp[j] = (f16)T[c4+j][r];
}

// ---------------- f16 MFMA GEMM, BK=64: C = act(A @ BT^T + bias), strided A/C ----------------
template<int ACT, int OUT16>
__global__ __launch_bounds__(256) void gemm_f16(
    const f16* __restrict__ A, const f16* __restrict__ BT,
    const float* __restrict__ bias, float* __restrict__ Cf, f16* __restrict__ Ch,
    int M, int N, int K, int lda, int ldc)
{
  __shared__ __align__(16) f16 As0[128*32];
  __shared__ __align__(16) f16 As1[128*32];
  __shared__ __align__(16) f16 Bs0[128*32];
  __shared__ __align__(16) f16 Bs1[128*32];
  int tid = threadIdx.x, lane = tid & 63, wave = tid >> 6;
  int wm = wave >> 1, wn = wave & 1;
  int n0 = blockIdx.x * 128, m0 = blockIdx.y * 128;
  f32x4 acc[4][4] = {};
  int seg0 = wave*2048 + lane*16;
  int ar = lane & 15, kq = (lane >> 4) * 8;

  for (int k0=0; k0<K; k0+=64){
    #pragma unroll
    for (int i=0;i<2;i++){
      int seg = seg0 + i*1024;
      int e = seg >> 1; int row = e >> 5; int kk = e & 31;
      const f16* ap = A  + (size_t)(m0+row)*lda + k0 + kk;
      const f16* bp = BT + (size_t)(n0+row)*K   + k0 + kk;
      gl2lds16(ap,      (char*)As0 + seg);
      gl2lds16(ap + 32, (char*)As1 + seg);
      gl2lds16(bp,      (char*)Bs0 + seg);
      gl2lds16(bp + 32, (char*)Bs1 + seg);
    }
    __syncthreads();
    {
      half8 af[4], bf[4];
      #pragma unroll
      for (int mi=0;mi<4;mi++) af[mi] = *(const half8*)&As0[(wm*64 + mi*16 + ar)*32 + kq];
      #pragma unroll
      for (int ni=0;ni<4;ni++) bf[ni] = *(const half8*)&Bs0[(wn*64 + ni*16 + ar)*32 + kq];
      #pragma unroll
      for (int mi=0;mi<4;mi++)
        #pragma unroll
        for (int ni=0;ni<4;ni++)
          acc[mi][ni] = __builtin_amdgcn_mfma_f32_16x16x32_f16(af[mi], bf[ni], acc[mi][ni], 0, 0, 0);
    }
    {
      half8 af[4], bf[4];
      #pragma unroll
      for (int mi=0;mi<4;mi++) af[mi] = *(const half8*)&As1[(wm*64 + mi*16 + ar)*32 + kq];
      #pragma unroll
      for (int ni=0;ni<4;ni++) bf[ni] = *(const half8*)&Bs1[(wn*64 + ni*16 + ar)*32 + kq];
      #pragma unroll
      for (int mi=0;mi<4;mi++)
        #pragma unroll
        for (int ni=0;ni<4;ni++)
          acc[mi][ni] = __builtin_amdgcn_mfma_f32_16x16x32_f16(af[mi], bf[ni], acc[mi][ni], 0, 0, 0);
    }
    __syncthreads();
  }
  int rb = (lane >> 4) * 4, cb = lane & 15;
  #pragma unroll
  for (int ni=0;ni<4;ni++){
    int cn = n0 + wn*64 + ni*16 + cb;
    float bz = bias[cn];
    #pragma unroll
    for (int mi=0;mi<4;mi++){
      int rm = m0 + wm*64 + mi*16 + rb;
      #pragma unroll
      for (int r=0;r<4;r++){
        float v = acc[mi][ni][r] + bz;
        if (ACT==1) v = 0.5f*v*(1.0f+erff(v*0.70710678118f));
        if (OUT16) Ch[(size_t)(rm+r)*ldc + cn] = (f16)v;
        else       Cf[(size_t)(rm+r)*ldc + cn] = v;
      }
    }
  }
}

// ---------------- beta/g projections ----------------
__global__ __launch_bounds__(256) void betag_kernel(
    const float* __restrict__ x, const float* __restrict__ Wb, const float* __restrict__ bb,
    const float* __restrict__ Wg, const float* __restrict__ bg,
    const int* __restrict__ mask, float* __restrict__ beta, float* __restrict__ g)
{
  __shared__ float Ws[384*25];
  for (int idx = threadIdx.x; idx < 384*12; idx += 256){
    int k = idx/12, j = idx - k*12;
    Ws[k*25+j]    = Wb[idx];
    Ws[k*25+12+j] = Wg[idx];
  }
  __syncthreads();
  int wv = threadIdx.x>>6, lane = threadIdx.x&63;
  int row = blockIdx.x*4 + wv;
  const float* xr = x + (size_t)row*DD;
  float accb[12], accg[12];
  #pragma unroll
  for (int j=0;j<12;j++){ accb[j]=0.f; accg[j]=0.f; }
  #pragma unroll
  for (int i=0;i<6;i++){
    int k = lane + 64*i;
    float xv = xr[k];
    const float* wr = &Ws[k*25];
    #pragma unroll
    for (int j=0;j<12;j++){ accb[j] += xv*wr[j]; accg[j] += xv*wr[12+j]; }
  }
  #pragma unroll
  for (int j=0;j<12;j++){
    #pragma unroll
    for (int off=32; off>=1; off>>=1){
      accb[j]+=__shfl_xor(accb[j],off);
      accg[j]+=__shfl_xor(accg[j],off);
    }
  }
  if (lane==0){
    float mk = (float)mask[row];
    #pragma unroll
    for (int j=0;j<12;j++){
      beta[(size_t)row*HH + j] = sigmoidf_(accb[j]+bb[j]) * mk;
      g[(size_t)row*HH + j]    = sigmoidf_(accg[j]+bg[j]);
    }
  }
}

// ---------------- DeltaNet dual-state scan: f16 LDS tiles + mixed-precision FMA ----------------
// One wave (=block) per (b,h). Lanes 0-31 fast state, 32-63 slow; lane owns col=lane&31.
// k/q stay f16 in REGISTERS (half8); dots/update use float(kh)*f32 so the compiler
// forms v_fma_mix_f32 — removes the 64 cvt/step tax of R8. State stays f32.
// No cross-lane ops in the step loop (R5 lesson); COMBINE per tile does the g-mix.
__global__ __launch_bounds__(64) void scan_kernel(
  f16* qkv,
  const float* __restrict__ bp, const float* __restrict__ gp,
  const float* __restrict__ flp, const float* __restrict__ slp)
{
  __shared__ __align__(16) f16 Kh[2][TB][32];
  __shared__ __align__(16) f16 Qh[2][TB][32];
  __shared__ __align__(16) f16 Vh[2][TB][32];
  __shared__ float Bg[2][2][TB];
  __shared__ float Of[TB][64];
  int blk = blockIdx.x;
  int b = blk / HH, h = blk - b*HH;
  int lane = threadIdx.x;
  int col = lane & 31;
  float a = sigmoidf_((lane < 32) ? flp[h] : slp[h]);
  float S[32];
  #pragma unroll
  for (int j=0;j<32;j++) S[j] = 0.f;
  size_t base = ((size_t)b*SS)*LDX + (size_t)h*DKK;
  f16* qb = qkv + base;                 // in-place out; aliases loads
  const f16* kb = qkv + base + 384;
  const f16* vb = qkv + base + 768;
  const float* bbp = bp + ((size_t)b*SS)*HH + h;
  const float* gbp = gp + ((size_t)b*SS)*HH + h;

  int st0 = lane >> 2, part = lane & 3;        // 4 lanes per step-row, 8 halves each
  uint4 kvr[2]; float bgv;

  // global loads: k into regs (normalization), q/v direct to LDS
  #define LOADG(T0,BUF) do {                                                   \
    _Pragma("unroll")                                                          \
    for (int r=0;r<2;r++){                                                     \
      kvr[r] = *(const uint4*)(kb + (size_t)((T0)+r*16+st0)*LDX + part*8);     \
      gl2lds16(qb + (size_t)((T0)+r*16+st0)*LDX + part*8,                      \
               (char*)&Qh[BUF][r*16][0] + lane*16);                            \
      gl2lds16(vb + (size_t)((T0)+r*16+st0)*LDX + part*8,                      \
               (char*)&Vh[BUF][r*16][0] + lane*16);                            \
    }                                                                          \
    int tb_ = (T0) + (lane & 31);                                              \
    bgv = (lane < 32) ? bbp[(size_t)tb_*HH] : gbp[(size_t)tb_*HH];             \
  } while(0)

  #define STAGE(BUF) do {                                                      \
    _Pragma("unroll")                                                          \
    for (int r=0;r<2;r++){                                                     \
      int s = r*16 + st0;                                                      \
      union { uint4 u; h2 hh[4]; } U; U.u = kvr[r];                            \
      float kf[8];                                                             \
      _Pragma("unroll")                                                        \
      for (int j=0;j<4;j++){ kf[2*j] = (float)U.hh[j].x; kf[2*j+1] = (float)U.hh[j].y; } \
      float ss = 0.f;                                                          \
      _Pragma("unroll")                                                        \
      for (int i=0;i<8;i++) ss += kf[i]*kf[i];                                 \
      ss += __shfl_xor(ss, 1); ss += __shfl_xor(ss, 2);                        \
      float sc = 1.0f/(sqrtf(ss)+1e-6f);                                       \
      half8 ko;                                                                \
      _Pragma("unroll")                                                        \
      for (int i=0;i<8;i++) ko[i] = (f16)(kf[i]*sc);                           \
      *(half8*)&Kh[BUF][s][part*8] = ko;                                       \
    }                                                                          \
    Bg[BUF][lane>>5][lane&31] = bgv;                                           \
  } while(0)

  // LDS -> f16 regs for one step (broadcast b128, no conversion)
  #define LDSTEP(BUF,S_,KH,QH,VT,BT) do {                                      \
    const half8* kh8_ = (const half8*)&Kh[BUF][S_][0];                         \
    const half8* qh8_ = (const half8*)&Qh[BUF][S_][0];                         \
    KH[0]=kh8_[0]; KH[1]=kh8_[1]; KH[2]=kh8_[2]; KH[3]=kh8_[3];                \
    QH[0]=qh8_[0]; QH[1]=qh8_[1]; QH[2]=qh8_[2]; QH[3]=qh8_[3];                \
    VT = (float)Vh[BUF][S_][col]; BT = Bg[BUF][0][S_];                         \
  } while(0)

  // mixed-precision step: float(kh)*f32 -> v_fma_mix_f32
  #define STEP(KH,QH,VT,BT,S_) do {                                           \
    float r0=0.f,r1=0.f,r2=0.f,r3=0.f;                                         \
    _Pragma("unroll")                                                          \
    for (int g_=0;g_<4;g_++){                                                  \
      _Pragma("unroll")                                                        \
      for (int e_=0;e_<8;e_+=4){                                               \
        r0 += S[g_*8+e_+0]*(float)KH[g_][e_+0];                                \
        r1 += S[g_*8+e_+1]*(float)KH[g_][e_+1];                                \
        r2 += S[g_*8+e_+2]*(float)KH[g_][e_+2];                                \
        r3 += S[g_*8+e_+3]*(float)KH[g_][e_+3];                                \
      }                                                                        \
    }                                                                          \
    float rf = (r0+r1)+(r2+r3);                                                \
    float c_ = (BT)*((VT) - rf);                                               \
    _Pragma("unroll")                                                          \
    for (int g_=0;g_<4;g_++)                                                   \
      _Pragma("unroll")                                                        \
      for (int e_=0;e_<8;e_++)                                                 \
        S[g_*8+e_] = a*S[g_*8+e_] + c_*(float)KH[g_][e_];                      \
    float o0=0.f,o1=0.f,o2=0.f,o3=0.f;                                         \
    _Pragma("unroll")                                                          \
    for (int g_=0;g_<4;g_++){                                                  \
      _Pragma("unroll")                                                        \
      for (int e_=0;e_<8;e_+=4){                                               \
        o0 += S[g_*8+e_+0]*(float)QH[g_][e_+0];                                \
        o1 += S[g_*8+e_+1]*(float)QH[g_][e_+1];                                \
        o2 += S[g_*8+e_+2]*(float)QH[g_][e_+2];                                \
        o3 += S[g_*8+e_+3]*(float)QH[g_][e_+3];                                \
      }                                                                        \
    }                                                                          \
    Of[S_][lane] = (o0+o1)+(o2+o3);                                            \
  } while(0)

  #define COMBINE(BUF,T0) do {                                                 \
    _Pragma("unroll")                                                          \
    for (int i=0;i<16;i++){                                                    \
      int idx = i*64 + lane;                                                   \
      int s_ = idx >> 5, c_ = idx & 31;                                        \
      float fv = Of[s_][c_];                                                   \
      float sv = Of[s_][c_+32];                                                \
      float gv = Bg[BUF][1][s_];                                               \
      qb[(size_t)((T0)+s_)*LDX + c_] = (f16)(gv*fv + (1.0f-gv)*sv);            \
    }                                                                          \
  } while(0)

  LOADG(0,0);
  STAGE(0);
  __syncthreads();

  half8 kA[4], qA[4], kB[4], qB[4];
  float vA, bA, vB, bB;

  for (int tile=0; tile<SS/TB; tile++){
    int buf = tile & 1;
    if (tile < SS/TB-1) LOADG((tile+1)*TB, 1-buf);   // k regs + q/v direct-to-LDS prefetch
    LDSTEP(buf, 0, kA, qA, vA, bA);
    #pragma unroll
    for (int s=0; s<TB; s+=2){
      if (s+1 < TB) LDSTEP(buf, s+1, kB, qB, vB, bB);
      STEP(kA, qA, vA, bA, s);
      if (s+2 < TB) LDSTEP(buf, s+2, kA, qA, vA, bA);
      STEP(kB, qB, vB, bB, s+1);
    }
    if (tile < SS/TB-1) STAGE(1-buf);
    COMBINE(buf, tile*TB);
    __syncthreads();
  }
  #undef LOADG
  #undef STAGE
  #undef LDSTEP
  #undef STEP
  #undef COMBINE
}

// ---------------- masked mean-pool + L2 normalize ----------------
__global__ __launch_bounds__(384) void pool_kernel(
    const float* __restrict__ x, const int* __restrict__ mask, float* __restrict__ out)
{
  __shared__ float red[384];
  __shared__ float tot;
  int b = blockIdx.x, d = threadIdx.x;
  const float* xb = x + (size_t)b*SS*DD;
  const int* mb = mask + b*SS;
  float s=0.f, sm=0.f;
  for (int t=0;t<SS;t++){ float m=(float)mb[t]; s += xb[(size_t)t*DD+d]*m; sm += m; }
  float emb = s / fmaxf(sm, 1e-9f);
  red[d] = emb*emb;
  __syncthreads();
  for (int off=192; off>=3; off>>=1){
    if (d < off) red[d] += red[d+off];
    __syncthreads();
  }
  if (d==0) tot = red[0]+red[1]+red[2];
  __syncthreads();
  out[(size_t)b*DD + d] = emb * rsqrtf(tot);
}

extern "C" void kernel_launch(void* const* d_in, const int* in_sizes, int n_in,
                              void* d_out, int out_size, void* d_ws, size_t ws_size,
                              hipStream_t stream)
{
  const int*   ids  = (const int*)d_in[0];
  const int*   amask= (const int*)d_in[1];
  const float* we   = (const float*)d_in[2];
  const float* pe   = (const float*)d_in[3];
  const float* te   = (const float*)d_in[4];
  const float* elnw = (const float*)d_in[5];
  const float* elnb = (const float*)d_in[6];
  const float* Wq   = (const float*)d_in[7];
  const float* bq   = (const float*)d_in[8];
  const float* Wk   = (const float*)d_in[9];
  const float* bk   = (const float*)d_in[10];
  const float* Wv   = (const float*)d_in[11];
  const float* bv   = (const float*)d_in[12];
  const float* Wb   = (const float*)d_in[13];
  const float* bb   = (const float*)d_in[14];
  const float* Wg   = (const float*)d_in[15];
  const float* bgp  = (const float*)d_in[16];
  const float* Wo   = (const float*)d_in[17];
  const float* bo   = (const float*)d_in[18];
  const float* fl   = (const float*)d_in[19];
  const float* sl   = (const float*)d_in[20];
  const float* alnw = (const float*)d_in[21];
  const float* alnb = (const float*)d_in[22];
  const float* W1   = (const float*)d_in[23];
  const float* b1   = (const float*)d_in[24];
  const float* W2   = (const float*)d_in[25];
  const float* b2   = (const float*)d_in[26];
  const float* flnw = (const float*)d_in[27];
  const float* flnb = (const float*)d_in[28];
  float* out = (float*)d_out;
  float* w = (float*)d_ws;

  // workspace (float slots), total 49,355,520 f = 197.4 MB
  float* x    = w;                      // 12,582,912 f
  f16*  xh   = (f16*)(w + 12582912);    // 12,582,912 h
  f16*  qkvh = (f16*)(w + 18874368);    // 37,748,736 h  [row][1152]
  float* f2   = w + 37748736;           //  6,291,456 f region
  f16*  f2h  = (f16*)f2;                // FFN2 out as f16 (chunk 16384x384)
  float* beta = f2 + 3145728;           //    393,216 f (disjoint from f2h chunk use? see note)
  float* gbuf = beta + 393216;          //    393,216 f
  f16*  wt   = (f16*)(w + 44040192);    // 10,616,832 h (all 6 layers)
  float* bqkv = w + 49348608;           //      6,912 f
  f16*  hbf  = qkvh;                    // FFN hidden chunk 16384x1536 h overlays qkv
  // note: f2h chunk = 16384*384 h = 3,145,728 f16 = 1,572,864 f slots; beta/gbuf at
  // f2+3145728 are beyond any f2h use and live across the whole layer safely.

  embed_ln_kernel<<<MROWS/4, 256, 0, stream>>>(ids, we, pe, te, elnw, elnb, x, xh);
  biaspack_kernel<<<27,256,0,stream>>>(bq, bk, bv, bqkv);
  wtrans_kernel<<<LL*1728,256,0,stream>>>(Wq, Wk, Wv, Wo, W1, W2, wt);

  for (int l=0;l<LL;l++){
    f16* wl = wt + (size_t)l*1769472;

    // fused QKV: [32768 x 1152] = xh @ [Wq|Wk|Wv]^T
    gemm_f16<0,1><<<dim3(9,256),256,0,stream>>>(xh, wl, bqkv + l*LDX, nullptr, qkvh,
                                                MROWS, LDX, DD, DD, LDX);

    betag_kernel<<<MROWS/4,256,0,stream>>>(x, Wb + (size_t)l*DD*HH, bb + l*HH,
                                           Wg + (size_t)l*DD*HH, bgp + l*HH,
                                           amask, beta, gbuf);
    scan_kernel<<<BB*HH,64,0,stream>>>(qkvh, beta, gbuf, fl + l*HH, sl + l*HH);

    // o-proj full-M: A = attn-out = qkv[:,0:384] (lda=1152), C(f16) -> dead k-slot qkv[:,384:768]
    gemm_f16<0,1><<<dim3(3,256),256,0,stream>>>(qkvh, wl+442368, bo+l*DD, nullptr,
                                                qkvh + 384, MROWS, DD, DD, LDX, LDX);
    add_ln_kernel<1><<<MROWS/4,256,0,stream>>>(x, xh, qkvh + 384, alnw+l*DD, alnb+l*DD, 0, LDX);

    // FFN in 2 row-chunks of 16384 (hidden overlays qkv); FFN2 out f16
    for (int c=0;c<2;c++){
      gemm_f16<1,1><<<dim3(12,128),256,0,stream>>>(xh + (size_t)c*16384*DD, wl+589824,
                                                   b1+l*FFF, nullptr, hbf, 16384, FFF, DD, DD, FFF);
      gemm_f16<0,1><<<dim3(3,128),256,0,stream>>>(hbf, wl+1179648, b2+l*DD, nullptr, f2h,
                                                  16384, DD, FFF, FFF, DD);
      add_ln_kernel<1><<<4096,256,0,stream>>>(x, xh, f2h, flnw+l*DD, flnb+l*DD, c*16384, DD);
    }
  }

  pool_kernel<<<BB,384,0,stream>>>(x, amask, out);
}

// Round 10
// 3531.195 us; speedup vs baseline: 1.1528x; 1.1528x over previous
//
#include <hip/hip_runtime.h>
#include <math.h>

#define DD 384
#define HH 12
#define DKK 32
#define LL 6
#define FFF 1536
#define BB 64
#define SS 512
#define MROWS (BB*SS)   // 32768
#define TB 32           // scan time-tile
#define LDX 1152        // qkv row stride

typedef _Float16 f16;
typedef _Float16 half8 __attribute__((ext_vector_type(8)));
typedef _Float16 h2 __attribute__((ext_vector_type(2)));
typedef float f32x4 __attribute__((ext_vector_type(4)));
typedef float f32x2 __attribute__((ext_vector_type(2)));

__device__ __forceinline__ float sigmoidf_(float x){ return 1.0f/(1.0f+expf(-x)); }

__device__ __forceinline__ float h2f_lo(unsigned int u){
  union { unsigned short s; f16 h; } c; c.s = (unsigned short)(u & 0xffffu); return (float)c.h;
}
__device__ __forceinline__ float h2f_hi(unsigned int u){
  union { unsigned short s; f16 h; } c; c.s = (unsigned short)(u >> 16); return (float)c.h;
}

__device__ __forceinline__ void gl2lds16(const void* g, void* l){
  __builtin_amdgcn_global_load_lds((const __attribute__((address_space(1))) void*)g,
                                   (__attribute__((address_space(3))) void*)l, 16, 0, 0);
}

// ---------------- embedding + LN (writes fp32 x and f16 xh) ----------------
__global__ __launch_bounds__(256) void embed_ln_kernel(
    const int* __restrict__ ids, const float* __restrict__ we,
    const float* __restrict__ pe, const float* __restrict__ te,
    const float* __restrict__ w, const float* __restrict__ b,
    float* __restrict__ x, f16* __restrict__ xh)
{
  int wv = threadIdx.x >> 6, lane = threadIdx.x & 63;
  int row = blockIdx.x * 4 + wv;
  int s = row & (SS-1);
  int id = ids[row];
  const float* wep = we + (size_t)id * DD;
  const float* pep = pe + (size_t)s * DD;
  float vals[6]; float sum = 0.f;
  #pragma unroll
  for (int i=0;i<6;i++){ int d = lane + 64*i; vals[i] = wep[d] + pep[d] + te[d]; sum += vals[i]; }
  #pragma unroll
  for (int off=32; off>=1; off>>=1) sum += __shfl_xor(sum, off);
  float mean = sum * (1.0f/DD);
  float vs = 0.f;
  #pragma unroll
  for (int i=0;i<6;i++){ float dv = vals[i]-mean; vs += dv*dv; }
  #pragma unroll
  for (int off=32; off>=1; off>>=1) vs += __shfl_xor(vs, off);
  float inv = rsqrtf(vs*(1.0f/DD) + 1e-12f);
  float* xr = x + (size_t)row*DD;
  f16* xhr = xh + (size_t)row*DD;
  #pragma unroll
  for (int i=0;i<6;i++){ int d = lane + 64*i; float o = (vals[i]-mean)*inv*w[d] + b[d]; xr[d]=o; xhr[d]=(f16)o; }
}

// ---------------- x = LN(x + y); y f32 (YH=0) or f16 (YH=1), stride ldy ----------------
template<int YH>
__global__ __launch_bounds__(256) void add_ln_kernel(
    float* __restrict__ x, f16* __restrict__ xh, const void* __restrict__ yp,
    const float* __restrict__ w, const float* __restrict__ b, int row0, int ldy)
{
  int wv = threadIdx.x >> 6, lane = threadIdx.x & 63;
  int rrel = blockIdx.x * 4 + wv;
  int row = row0 + rrel;
  float* xr = x + (size_t)row*DD;
  f16* xhr = xh + (size_t)row*DD;
  float vals[6]; float sum = 0.f;
  #pragma unroll
  for (int i=0;i<6;i++){
    int d = lane + 64*i;
    float yv;
    if (YH) yv = (float)((const f16*)yp)[(size_t)rrel*ldy + d];
    else    yv = ((const float*)yp)[(size_t)rrel*ldy + d];
    vals[i] = xr[d] + yv; sum += vals[i];
  }
  #pragma unroll
  for (int off=32; off>=1; off>>=1) sum += __shfl_xor(sum, off);
  float mean = sum * (1.0f/DD);
  float vs = 0.f;
  #pragma unroll
  for (int i=0;i<6;i++){ float dv = vals[i]-mean; vs += dv*dv; }
  #pragma unroll
  for (int off=32; off>=1; off>>=1) vs += __shfl_xor(vs, off);
  float inv = rsqrtf(vs*(1.0f/DD) + 1e-12f);
  #pragma unroll
  for (int i=0;i<6;i++){ int d = lane + 64*i; float o = (vals[i]-mean)*inv*w[d] + b[d]; xr[d]=o; xhr[d]=(f16)o; }
}

// ---------------- bias pack: [bq;bk;bv] per layer -> 1152 each ----------------
__global__ __launch_bounds__(256) void biaspack_kernel(
    const float* __restrict__ bq, const float* __restrict__ bk, const float* __restrict__ bv,
    float* __restrict__ dst)
{
  int i = blockIdx.x*256 + threadIdx.x;   // 6912 total
  if (i >= LL*LDX) return;
  int l = i / LDX, r = i - l*LDX;
  float v;
  if (r < 384) v = bq[l*DD + r];
  else if (r < 768) v = bk[l*DD + r-384];
  else v = bv[l*DD + r-768];
  dst[i] = v;
}

// ---------------- weight transpose + f32->f16, ALL layers in one dispatch ----------------
__global__ __launch_bounds__(256) void wtrans_kernel(
  const float* __restrict__ Wq, const float* __restrict__ Wk, const float* __restrict__ Wv,
  const float* __restrict__ Wo, const float* __restrict__ W1, const float* __restrict__ W2,
  f16* __restrict__ Wt)
{
  __shared__ float T[32][33];
  int l = blockIdx.x / 1728, bidx = blockIdx.x % 1728;
  const float* src; f16* dst; int K, N, tile;
  if (bidx < 576){ int m = bidx/144; tile = bidx - m*144; K=384; N=384;
    const float* w4[4] = {Wq + (size_t)l*147456, Wk + (size_t)l*147456,
                          Wv + (size_t)l*147456, Wo + (size_t)l*147456};
    src = w4[m]; dst = Wt + (size_t)l*1769472 + m*147456; }
  else if (bidx < 1152){ tile = bidx-576; K=384; N=1536;
    src = W1 + (size_t)l*589824; dst = Wt + (size_t)l*1769472 + 589824; }
  else { tile = bidx-1152; K=1536; N=384;
    src = W2 + (size_t)l*589824; dst = Wt + (size_t)l*1769472 + 1179648; }
  int tN = N>>5;
  int tk = tile / tN, tn = tile - tk*tN;
  int k0 = tk<<5, n0 = tn<<5;
  int r = threadIdx.x >> 3, c4 = (threadIdx.x & 7) << 2;
  float4 vv = *(const float4*)(src + (size_t)(k0+r)*N + n0 + c4);
  T[r][c4+0]=vv.x; T[r][c4+1]=vv.y; T[r][c4+2]=vv.z; T[r][c4+3]=vv.w;
  __syncthreads();
  f16* dp = dst + (size_t)(n0+r)*K + k0 + c4;
  #pragma unroll
  for (int j=0;j<4;j++) dp[j] = (f16)T[c4+j][r];
}

// ---------------- f16 MFMA GEMM, BK=64: C = act(A @ BT^T + bias), strided A/C ----------------
template<int ACT, int OUT16>
__global__ __launch_bounds__(256) void gemm_f16(
    const f16* __restrict__ A, const f16* __restrict__ BT,
    const float* __restrict__ bias, float* __restrict__ Cf, f16* __restrict__ Ch,
    int M, int N, int K, int lda, int ldc)
{
  __shared__ __align__(16) f16 As0[128*32];
  __shared__ __align__(16) f16 As1[128*32];
  __shared__ __align__(16) f16 Bs0[128*32];
  __shared__ __align__(16) f16 Bs1[128*32];
  int tid = threadIdx.x, lane = tid & 63, wave = tid >> 6;
  int wm = wave >> 1, wn = wave & 1;
  int n0 = blockIdx.x * 128, m0 = blockIdx.y * 128;
  f32x4 acc[4][4] = {};
  int seg0 = wave*2048 + lane*16;
  int ar = lane & 15, kq = (lane >> 4) * 8;

  for (int k0=0; k0<K; k0+=64){
    #pragma unroll
    for (int i=0;i<2;i++){
      int seg = seg0 + i*1024;
      int e = seg >> 1; int row = e >> 5; int kk = e & 31;
      const f16* ap = A  + (size_t)(m0+row)*lda + k0 + kk;
      const f16* bp = BT + (size_t)(n0+row)*K   + k0 + kk;
      gl2lds16(ap,      (char*)As0 + seg);
      gl2lds16(ap + 32, (char*)As1 + seg);
      gl2lds16(bp,      (char*)Bs0 + seg);
      gl2lds16(bp + 32, (char*)Bs1 + seg);
    }
    __syncthreads();
    {
      half8 af[4], bf[4];
      #pragma unroll
      for (int mi=0;mi<4;mi++) af[mi] = *(const half8*)&As0[(wm*64 + mi*16 + ar)*32 + kq];
      #pragma unroll
      for (int ni=0;ni<4;ni++) bf[ni] = *(const half8*)&Bs0[(wn*64 + ni*16 + ar)*32 + kq];
      #pragma unroll
      for (int mi=0;mi<4;mi++)
        #pragma unroll
        for (int ni=0;ni<4;ni++)
          acc[mi][ni] = __builtin_amdgcn_mfma_f32_16x16x32_f16(af[mi], bf[ni], acc[mi][ni], 0, 0, 0);
    }
    {
      half8 af[4], bf[4];
      #pragma unroll
      for (int mi=0;mi<4;mi++) af[mi] = *(const half8*)&As1[(wm*64 + mi*16 + ar)*32 + kq];
      #pragma unroll
      for (int ni=0;ni<4;ni++) bf[ni] = *(const half8*)&Bs1[(wn*64 + ni*16 + ar)*32 + kq];
      #pragma unroll
      for (int mi=0;mi<4;mi++)
        #pragma unroll
        for (int ni=0;ni<4;ni++)
          acc[mi][ni] = __builtin_amdgcn_mfma_f32_16x16x32_f16(af[mi], bf[ni], acc[mi][ni], 0, 0, 0);
    }
    __syncthreads();
  }
  int rb = (lane >> 4) * 4, cb = lane & 15;
  #pragma unroll
  for (int ni=0;ni<4;ni++){
    int cn = n0 + wn*64 + ni*16 + cb;
    float bz = bias[cn];
    #pragma unroll
    for (int mi=0;mi<4;mi++){
      int rm = m0 + wm*64 + mi*16 + rb;
      #pragma unroll
      for (int r=0;r<4;r++){
        float v = acc[mi][ni][r] + bz;
        if (ACT==1) v = 0.5f*v*(1.0f+erff(v*0.70710678118f));
        if (OUT16) Ch[(size_t)(rm+r)*ldc + cn] = (f16)v;
        else       Cf[(size_t)(rm+r)*ldc + cn] = v;
      }
    }
  }
}

// ---------------- beta/g projections ----------------
__global__ __launch_bounds__(256) void betag_kernel(
    const float* __restrict__ x, const float* __restrict__ Wb, const float* __restrict__ bb,
    const float* __restrict__ Wg, const float* __restrict__ bg,
    const int* __restrict__ mask, float* __restrict__ beta, float* __restrict__ g)
{
  __shared__ float Ws[384*25];
  for (int idx = threadIdx.x; idx < 384*12; idx += 256){
    int k = idx/12, j = idx - k*12;
    Ws[k*25+j]    = Wb[idx];
    Ws[k*25+12+j] = Wg[idx];
  }
  __syncthreads();
  int wv = threadIdx.x>>6, lane = threadIdx.x&63;
  int row = blockIdx.x*4 + wv;
  const float* xr = x + (size_t)row*DD;
  float accb[12], accg[12];
  #pragma unroll
  for (int j=0;j<12;j++){ accb[j]=0.f; accg[j]=0.f; }
  #pragma unroll
  for (int i=0;i<6;i++){
    int k = lane + 64*i;
    float xv = xr[k];
    const float* wr = &Ws[k*25];
    #pragma unroll
    for (int j=0;j<12;j++){ accb[j] += xv*wr[j]; accg[j] += xv*wr[12+j]; }
  }
  #pragma unroll
  for (int j=0;j<12;j++){
    #pragma unroll
    for (int off=32; off>=1; off>>=1){
      accb[j]+=__shfl_xor(accb[j],off);
      accg[j]+=__shfl_xor(accg[j],off);
    }
  }
  if (lane==0){
    float mk = (float)mask[row];
    #pragma unroll
    for (int j=0;j<12;j++){
      beta[(size_t)row*HH + j] = sigmoidf_(accb[j]+bb[j]) * mk;
      g[(size_t)row*HH + j]    = sigmoidf_(accg[j]+bg[j]);
    }
  }
}

// ---------------- DeltaNet dual-state scan (R6 config: f32 LDS + packed f32x2 math) ----------------
// Best measured config (153 us in R6; f16-LDS and fma_mix variants both slower — R8/R9).
// One wave (=block) per (b,h). Lanes 0-31 fast, 32-63 slow; lane owns col=lane&31.
// qkv layout [row][1152]: q|k|v; out in-place over q. k-norm fused at staging.
// No cross-lane ops in step loop (R5); per-tile COMBINE does the fast/slow g-mix.
__global__ __launch_bounds__(64) void scan_kernel(
  f16* qkv,
  const float* __restrict__ bp, const float* __restrict__ gp,
  const float* __restrict__ flp, const float* __restrict__ slp)
{
  __shared__ float Kf[2][TB][32];
  __shared__ float Qf[2][TB][32];
  __shared__ float Vf[2][TB][32];
  __shared__ float Bg[2][2][TB];
  __shared__ float Of[TB][64];
  int blk = blockIdx.x;
  int b = blk / HH, h = blk - b*HH;
  int lane = threadIdx.x;
  int col = lane & 31;
  float a = sigmoidf_((lane < 32) ? flp[h] : slp[h]);
  f32x2 a2 = {a, a};
  f32x2 S2[16];
  #pragma unroll
  for (int j=0;j<16;j++) S2[j] = (f32x2){0.f,0.f};
  size_t base = ((size_t)b*SS)*LDX + (size_t)h*DKK;
  f16* qb = qkv + base;
  const f16* kb = qkv + base + 384;
  const f16* vb = qkv + base + 768;
  const float* bbp = bp + ((size_t)b*SS)*HH + h;
  const float* gbp = gp + ((size_t)b*SS)*HH + h;

  int st0 = lane >> 2, part = lane & 3;
  uint4 kv[2], qv[2], vv[2]; float bgv;

  #define LOADG(T0) do {                                                       \
    _Pragma("unroll")                                                          \
    for (int r=0;r<2;r++){                                                     \
      int st = (T0) + r*16 + st0;                                              \
      size_t off = (size_t)st*LDX + part*8;                                    \
      kv[r] = *(const uint4*)(kb + off);                                       \
      qv[r] = *(const uint4*)(qb + off);                                       \
      vv[r] = *(const uint4*)(vb + off);                                       \
    }                                                                          \
    int tb_ = (T0) + (lane & 31);                                              \
    bgv = (lane < 32) ? bbp[(size_t)tb_*HH] : gbp[(size_t)tb_*HH];             \
  } while(0)

  #define STAGE(BUF) do {                                                      \
    _Pragma("unroll")                                                          \
    for (int r=0;r<2;r++){                                                     \
      int s = r*16 + st0;                                                      \
      float kf[8], qf[8], vf[8];                                               \
      kf[0]=h2f_lo(kv[r].x); kf[1]=h2f_hi(kv[r].x); kf[2]=h2f_lo(kv[r].y);     \
      kf[3]=h2f_hi(kv[r].y); kf[4]=h2f_lo(kv[r].z); kf[5]=h2f_hi(kv[r].z);     \
      kf[6]=h2f_lo(kv[r].w); kf[7]=h2f_hi(kv[r].w);                            \
      qf[0]=h2f_lo(qv[r].x); qf[1]=h2f_hi(qv[r].x); qf[2]=h2f_lo(qv[r].y);     \
      qf[3]=h2f_hi(qv[r].y); qf[4]=h2f_lo(qv[r].z); qf[5]=h2f_hi(qv[r].z);     \
      qf[6]=h2f_lo(qv[r].w); qf[7]=h2f_hi(qv[r].w);                            \
      vf[0]=h2f_lo(vv[r].x); vf[1]=h2f_hi(vv[r].x); vf[2]=h2f_lo(vv[r].y);     \
      vf[3]=h2f_hi(vv[r].y); vf[4]=h2f_lo(vv[r].z); vf[5]=h2f_hi(vv[r].z);     \
      vf[6]=h2f_lo(vv[r].w); vf[7]=h2f_hi(vv[r].w);                            \
      float ss = 0.f;                                                          \
      _Pragma("unroll")                                                        \
      for (int i=0;i<8;i++) ss += kf[i]*kf[i];                                 \
      ss += __shfl_xor(ss, 1); ss += __shfl_xor(ss, 2);                        \
      float sc = 1.0f/(sqrtf(ss)+1e-6f);                                       \
      float4 t;                                                                \
      t.x=kf[0]*sc; t.y=kf[1]*sc; t.z=kf[2]*sc; t.w=kf[3]*sc;                  \
      *(float4*)&Kf[BUF][s][part*8] = t;                                       \
      t.x=kf[4]*sc; t.y=kf[5]*sc; t.z=kf[6]*sc; t.w=kf[7]*sc;                  \
      *(float4*)&Kf[BUF][s][part*8+4] = t;                                     \
      t.x=qf[0]; t.y=qf[1]; t.z=qf[2]; t.w=qf[3];                              \
      *(float4*)&Qf[BUF][s][part*8] = t;                                       \
      t.x=qf[4]; t.y=qf[5]; t.z=qf[6]; t.w=qf[7];                              \
      *(float4*)&Qf[BUF][s][part*8+4] = t;                                     \
      t.x=vf[0]; t.y=vf[1]; t.z=vf[2]; t.w=vf[3];                              \
      *(float4*)&Vf[BUF][s][part*8] = t;                                       \
      t.x=vf[4]; t.y=vf[5]; t.z=vf[6]; t.w=vf[7];                              \
      *(float4*)&Vf[BUF][s][part*8+4] = t;                                     \
    }                                                                          \
    Bg[BUF][lane>>5][lane&31] = bgv;                                           \
  } while(0)

  #define LDSTEP(BUF,S,KR,QR,VT,BT) do {                                       \
    const float4* k4_ = (const float4*)&Kf[BUF][S][0];                         \
    const float4* q4_ = (const float4*)&Qf[BUF][S][0];                         \
    _Pragma("unroll")                                                          \
    for (int j=0;j<8;j++){ KR[j]=k4_[j]; QR[j]=q4_[j]; }                       \
    VT = Vf[BUF][S][col]; BT = Bg[BUF][0][S];                                  \
  } while(0)

  #define STEP(KR,QR,VT,BT,S) do {                                            \
    const f32x2* k2_ = (const f32x2*)KR;                                       \
    const f32x2* q2_ = (const f32x2*)QR;                                       \
    f32x2 rA={0.f,0.f},rB={0.f,0.f},rC={0.f,0.f},rD={0.f,0.f};                 \
    _Pragma("unroll")                                                          \
    for (int j=0;j<16;j+=4){                                                   \
      rA += S2[j+0]*k2_[j+0]; rB += S2[j+1]*k2_[j+1];                          \
      rC += S2[j+2]*k2_[j+2]; rD += S2[j+3]*k2_[j+3]; }                        \
    f32x2 rr = (rA+rB)+(rC+rD);                                                \
    float rf = rr.x + rr.y;                                                    \
    float c_ = (BT)*((VT) - rf);                                               \
    f32x2 c2 = {c_, c_};                                                       \
    _Pragma("unroll")                                                          \
    for (int j=0;j<16;j++) S2[j] = a2*S2[j] + c2*k2_[j];                       \
    f32x2 oA={0.f,0.f},oB={0.f,0.f},oC={0.f,0.f},oD={0.f,0.f};                 \
    _Pragma("unroll")                                                          \
    for (int j=0;j<16;j+=4){                                                   \
      oA += S2[j+0]*q2_[j+0]; oB += S2[j+1]*q2_[j+1];                          \
      oC += S2[j+2]*q2_[j+2]; oD += S2[j+3]*q2_[j+3]; }                        \
    f32x2 oo = (oA+oB)+(oC+oD);                                                \
    Of[S][lane] = oo.x + oo.y;                                                 \
  } while(0)

  #define COMBINE(BUF,T0) do {                                                 \
    _Pragma("unroll")                                                          \
    for (int i=0;i<16;i++){                                                    \
      int idx = i*64 + lane;                                                   \
      int s_ = idx >> 5, c_ = idx & 31;                                        \
      float fv = Of[s_][c_];                                                   \
      float sv = Of[s_][c_+32];                                                \
      float gv = Bg[BUF][1][s_];                                               \
      qb[(size_t)((T0)+s_)*LDX + c_] = (f16)(gv*fv + (1.0f-gv)*sv);            \
    }                                                                          \
  } while(0)

  LOADG(0);
  STAGE(0);
  __syncthreads();

  float4 kA[8], qA[8], kB[8], qB[8];
  float vA, bA, vB, bB;

  for (int tile=0; tile<SS/TB; tile++){
    int buf = tile & 1;
    if (tile < SS/TB-1) LOADG((tile+1)*TB);
    LDSTEP(buf, 0, kA, qA, vA, bA);
    #pragma unroll
    for (int s=0; s<TB; s+=2){
      if (s+1 < TB) LDSTEP(buf, s+1, kB, qB, vB, bB);
      STEP(kA, qA, vA, bA, s);
      if (s+2 < TB) LDSTEP(buf, s+2, kA, qA, vA, bA);
      STEP(kB, qB, vB, bB, s+1);
    }
    if (tile < SS/TB-1) STAGE(1-buf);
    COMBINE(buf, tile*TB);
    __syncthreads();
  }
  #undef LOADG
  #undef STAGE
  #undef LDSTEP
  #undef STEP
  #undef COMBINE
}

// ---------------- masked mean-pool + L2 normalize ----------------
__global__ __launch_bounds__(384) void pool_kernel(
    const float* __restrict__ x, const int* __restrict__ mask, float* __restrict__ out)
{
  __shared__ float red[384];
  __shared__ float tot;
  int b = blockIdx.x, d = threadIdx.x;
  const float* xb = x + (size_t)b*SS*DD;
  const int* mb = mask + b*SS;
  float s=0.f, sm=0.f;
  for (int t=0;t<SS;t++){ float m=(float)mb[t]; s += xb[(size_t)t*DD+d]*m; sm += m; }
  float emb = s / fmaxf(sm, 1e-9f);
  red[d] = emb*emb;
  __syncthreads();
  for (int off=192; off>=3; off>>=1){
    if (d < off) red[d] += red[d+off];
    __syncthreads();
  }
  if (d==0) tot = red[0]+red[1]+red[2];
  __syncthreads();
  out[(size_t)b*DD + d] = emb * rsqrtf(tot);
}

extern "C" void kernel_launch(void* const* d_in, const int* in_sizes, int n_in,
                              void* d_out, int out_size, void* d_ws, size_t ws_size,
                              hipStream_t stream)
{
  const int*   ids  = (const int*)d_in[0];
  const int*   amask= (const int*)d_in[1];
  const float* we   = (const float*)d_in[2];
  const float* pe   = (const float*)d_in[3];
  const float* te   = (const float*)d_in[4];
  const float* elnw = (const float*)d_in[5];
  const float* elnb = (const float*)d_in[6];
  const float* Wq   = (const float*)d_in[7];
  const float* bq   = (const float*)d_in[8];
  const float* Wk   = (const float*)d_in[9];
  const float* bk   = (const float*)d_in[10];
  const float* Wv   = (const float*)d_in[11];
  const float* bv   = (const float*)d_in[12];
  const float* Wb   = (const float*)d_in[13];
  const float* bb   = (const float*)d_in[14];
  const float* Wg   = (const float*)d_in[15];
  const float* bgp  = (const float*)d_in[16];
  const float* Wo   = (const float*)d_in[17];
  const float* bo   = (const float*)d_in[18];
  const float* fl   = (const float*)d_in[19];
  const float* sl   = (const float*)d_in[20];
  const float* alnw = (const float*)d_in[21];
  const float* alnb = (const float*)d_in[22];
  const float* W1   = (const float*)d_in[23];
  const float* b1   = (const float*)d_in[24];
  const float* W2   = (const float*)d_in[25];
  const float* b2   = (const float*)d_in[26];
  const float* flnw = (const float*)d_in[27];
  const float* flnb = (const float*)d_in[28];
  float* out = (float*)d_out;
  float* w = (float*)d_ws;

  // workspace (float slots), total 49,355,520 f = 197.4 MB
  float* x    = w;                      // 12,582,912 f
  f16*  xh   = (f16*)(w + 12582912);    // 12,582,912 h
  f16*  qkvh = (f16*)(w + 18874368);    // 37,748,736 h  [row][1152]
  float* f2   = w + 37748736;           //  6,291,456 f region
  f16*  f2h  = (f16*)f2;                // FFN2 out as f16 (chunk 16384x384)
  float* beta = f2 + 3145728;           //    393,216 f (beyond f2h chunk use)
  float* gbuf = beta + 393216;          //    393,216 f
  f16*  wt   = (f16*)(w + 44040192);    // 10,616,832 h (all 6 layers)
  float* bqkv = w + 49348608;           //      6,912 f
  f16*  hbf  = qkvh;                    // FFN hidden chunk 16384x1536 h overlays qkv

  embed_ln_kernel<<<MROWS/4, 256, 0, stream>>>(ids, we, pe, te, elnw, elnb, x, xh);
  biaspack_kernel<<<27,256,0,stream>>>(bq, bk, bv, bqkv);
  wtrans_kernel<<<LL*1728,256,0,stream>>>(Wq, Wk, Wv, Wo, W1, W2, wt);

  for (int l=0;l<LL;l++){
    f16* wl = wt + (size_t)l*1769472;

    // fused QKV: [32768 x 1152] = xh @ [Wq|Wk|Wv]^T
    gemm_f16<0,1><<<dim3(9,256),256,0,stream>>>(xh, wl, bqkv + l*LDX, nullptr, qkvh,
                                                MROWS, LDX, DD, DD, LDX);

    betag_kernel<<<MROWS/4,256,0,stream>>>(x, Wb + (size_t)l*DD*HH, bb + l*HH,
                                           Wg + (size_t)l*DD*HH, bgp + l*HH,
                                           amask, beta, gbuf);
    scan_kernel<<<BB*HH,64,0,stream>>>(qkvh, beta, gbuf, fl + l*HH, sl + l*HH);

    // o-proj full-M: A = attn-out = qkv[:,0:384] (lda=1152), C(f16) -> dead k-slot qkv[:,384:768]
    gemm_f16<0,1><<<dim3(3,256),256,0,stream>>>(qkvh, wl+442368, bo+l*DD, nullptr,
                                                qkvh + 384, MROWS, DD, DD, LDX, LDX);
    add_ln_kernel<1><<<MROWS/4,256,0,stream>>>(x, xh, qkvh + 384, alnw+l*DD, alnb+l*DD, 0, LDX);

    // FFN in 2 row-chunks of 16384 (hidden overlays qkv); FFN2 out f16
    for (int c=0;c<2;c++){
      gemm_f16<1,1><<<dim3(12,128),256,0,stream>>>(xh + (size_t)c*16384*DD, wl+589824,
                                                   b1+l*FFF, nullptr, hbf, 16384, FFF, DD, DD, FFF);
      gemm_f16<0,1><<<dim3(3,128),256,0,stream>>>(hbf, wl+1179648, b2+l*DD, nullptr, f2h,
                                                  16384, DD, FFF, FFF, DD);
      add_ln_kernel<1><<<4096,256,0,stream>>>(x, xh, f2h, flnw+l*DD, flnb+l*DD, c*16384, DD);
    }
  }

  pool_kernel<<<BB,384,0,stream>>>(x, amask, out);
}